// Round 1
// baseline (236.216 us; speedup 1.0000x reference)
//
#include <hip/hip_runtime.h>

#define NCLS 1024
#define EPS_C 1e-5f

// ---------------- Kernel 1: per-class histogram of target ----------------
__global__ __launch_bounds__(256) void hist_kernel(const int* __restrict__ tgt,
                                                   unsigned int* __restrict__ counts,
                                                   int B) {
    __shared__ unsigned int h[NCLS];
    for (int i = threadIdx.x; i < NCLS; i += blockDim.x) h[i] = 0u;
    __syncthreads();
    for (int i = blockIdx.x * blockDim.x + threadIdx.x; i < B;
         i += gridDim.x * blockDim.x) {
        int t = tgt[i] & (NCLS - 1);
        atomicAdd(&h[t], 1u);
    }
    __syncthreads();
    for (int i = threadIdx.x; i < NCLS; i += blockDim.x) {
        unsigned int v = h[i];
        if (v) atomicAdd(&counts[i], v);
    }
}

// ---------------- Kernel 2: w[j] = min(counts)/counts[j] + eps ----------------
__global__ __launch_bounds__(1024) void weights_kernel(const unsigned int* __restrict__ counts,
                                                       float* __restrict__ w) {
    __shared__ float smin[16];
    int tid = threadIdx.x;            // 0..1023
    float c = (float)counts[tid];
    float m = c;
    #pragma unroll
    for (int off = 32; off > 0; off >>= 1) m = fminf(m, __shfl_xor(m, off));
    if ((tid & 63) == 0) smin[tid >> 6] = m;
    __syncthreads();
    if (tid == 0) {
        float mm = smin[0];
        #pragma unroll
        for (int i = 1; i < 16; ++i) mm = fminf(mm, smin[i]);
        smin[0] = mm;
    }
    __syncthreads();
    float cmin = smin[0];
    w[tid] = cmin / c + EPS_C;
}

// ---------------- Kernel 3: per-row softmax + focal loss, accumulate ----------------
// One 64-lane wave per row; 4 rows per 256-thread block.
__global__ __launch_bounds__(256) void loss_kernel(const float* __restrict__ inp,
                                                   const int* __restrict__ tgt,
                                                   const float* __restrict__ w,
                                                   float* __restrict__ loss_sum,
                                                   int B) {
    const int wave = threadIdx.x >> 6;
    const int lane = threadIdx.x & 63;
    const int row  = blockIdx.x * 4 + wave;

    __shared__ float partial[4];
    float loss = 0.0f;

    if (row < B) {
        const float4* rp = (const float4*)(inp + (size_t)row * NCLS);
        // 16 contiguous float4 loads per wave-step: lane i reads float4 #(i + k*64)
        float4 v0 = rp[lane];
        float4 v1 = rp[lane + 64];
        float4 v2 = rp[lane + 128];
        float4 v3 = rp[lane + 192];

        float m = fmaxf(fmaxf(fmaxf(v0.x, v0.y), fmaxf(v0.z, v0.w)),
                        fmaxf(fmaxf(v1.x, v1.y), fmaxf(v1.z, v1.w)));
        m = fmaxf(m, fmaxf(fmaxf(fmaxf(v2.x, v2.y), fmaxf(v2.z, v2.w)),
                           fmaxf(fmaxf(v3.x, v3.y), fmaxf(v3.z, v3.w))));
        #pragma unroll
        for (int off = 32; off > 0; off >>= 1) m = fmaxf(m, __shfl_xor(m, off));

        float s = __expf(v0.x - m) + __expf(v0.y - m) + __expf(v0.z - m) + __expf(v0.w - m)
                + __expf(v1.x - m) + __expf(v1.y - m) + __expf(v1.z - m) + __expf(v1.w - m)
                + __expf(v2.x - m) + __expf(v2.y - m) + __expf(v2.z - m) + __expf(v2.w - m)
                + __expf(v3.x - m) + __expf(v3.y - m) + __expf(v3.z - m) + __expf(v3.w - m);
        #pragma unroll
        for (int off = 32; off > 0; off >>= 1) s += __shfl_xor(s, off);

        if (lane == 0) {
            int t = tgt[row] & (NCLS - 1);
            float xt = inp[(size_t)row * NCLS + t];
            float logZ  = m + __logf(s);
            float logpt = xt - logZ;
            float pt    = __expf(logpt);
            float om    = 1.0f - pt;
            loss = -om * om * logpt * w[t];
        }
    }
    if (lane == 0) partial[wave] = loss;
    __syncthreads();
    if (threadIdx.x == 0) {
        atomicAdd(loss_sum, partial[0] + partial[1] + partial[2] + partial[3]);
    }
}

// ---------------- Kernel 4: finalize ----------------
__global__ void finalize_kernel(const float* __restrict__ loss_sum,
                                float* __restrict__ out, float invB) {
    out[0] = loss_sum[0] * invB;
}

extern "C" void kernel_launch(void* const* d_in, const int* in_sizes, int n_in,
                              void* d_out, int out_size, void* d_ws, size_t ws_size,
                              hipStream_t stream) {
    const float* inp = (const float*)d_in[0];
    const int*   tgt = (const int*)d_in[1];
    const int B = in_sizes[1];          // 65536

    unsigned int* counts = (unsigned int*)d_ws;
    float* w    = (float*)((char*)d_ws + 4096);
    float* lsum = (float*)((char*)d_ws + 8192);

    // zero counts + loss accumulator each call (captured in the graph)
    hipMemsetAsync(d_ws, 0, 8192 + 256, stream);

    hist_kernel<<<256, 256, 0, stream>>>(tgt, counts, B);
    weights_kernel<<<1, 1024, 0, stream>>>(counts, w);
    loss_kernel<<<(B + 3) / 4, 256, 0, stream>>>(inp, tgt, w, lsum, B);
    finalize_kernel<<<1, 1, 0, stream>>>(lsum, (float*)d_out, 1.0f / (float)B);
}

// Round 2
// 61.374 us; speedup vs baseline: 3.8488x; 3.8488x over previous
//
#include <hip/hip_runtime.h>

#define NCLS 1024
#define EPS_C 1e-5f
#define LOSS_BLOCKS 2048   // 2048 blocks * 4 waves = 8192 waves; 8 rows/wave at B=65536

// ---------------- Kernel 1: per-class histogram of target ----------------
__global__ __launch_bounds__(256) void hist_kernel(const int* __restrict__ tgt,
                                                   unsigned int* __restrict__ counts,
                                                   int B) {
    __shared__ unsigned int h[NCLS];
    for (int i = threadIdx.x; i < NCLS; i += blockDim.x) h[i] = 0u;
    __syncthreads();
    for (int i = blockIdx.x * blockDim.x + threadIdx.x; i < B;
         i += gridDim.x * blockDim.x) {
        int t = tgt[i] & (NCLS - 1);
        atomicAdd(&h[t], 1u);
    }
    __syncthreads();
    for (int i = threadIdx.x; i < NCLS; i += blockDim.x) {
        unsigned int v = h[i];
        if (v) atomicAdd(&counts[i], v);
    }
}

// ---------------- Kernel 2: w[j] = min(counts)/counts[j] + eps ----------------
__global__ __launch_bounds__(1024) void weights_kernel(const unsigned int* __restrict__ counts,
                                                       float* __restrict__ w) {
    __shared__ float smin[16];
    int tid = threadIdx.x;            // 0..1023
    float c = (float)counts[tid];
    float m = c;
    #pragma unroll
    for (int off = 32; off > 0; off >>= 1) m = fminf(m, __shfl_xor(m, off));
    if ((tid & 63) == 0) smin[tid >> 6] = m;
    __syncthreads();
    if (tid == 0) {
        float mm = smin[0];
        #pragma unroll
        for (int i = 1; i < 16; ++i) mm = fminf(mm, smin[i]);
        smin[0] = mm;
    }
    __syncthreads();
    float cmin = smin[0];
    w[tid] = cmin / c + EPS_C;
}

// ---------------- helpers ----------------
__device__ __forceinline__ float max16(float4 a, float4 b, float4 c, float4 d) {
    float m = fmaxf(fmaxf(fmaxf(a.x, a.y), fmaxf(a.z, a.w)),
                    fmaxf(fmaxf(b.x, b.y), fmaxf(b.z, b.w)));
    return fmaxf(m, fmaxf(fmaxf(fmaxf(c.x, c.y), fmaxf(c.z, c.w)),
                          fmaxf(fmaxf(d.x, d.y), fmaxf(d.z, d.w))));
}

__device__ __forceinline__ float sumexp16(float4 a, float4 b, float4 c, float4 d, float m) {
    return __expf(a.x - m) + __expf(a.y - m) + __expf(a.z - m) + __expf(a.w - m)
         + __expf(b.x - m) + __expf(b.y - m) + __expf(b.z - m) + __expf(b.w - m)
         + __expf(c.x - m) + __expf(c.y - m) + __expf(c.z - m) + __expf(c.w - m)
         + __expf(d.x - m) + __expf(d.y - m) + __expf(d.z - m) + __expf(d.w - m);
}

// Extract element t (0..1023) of the row held across the wave's registers.
// Lane L holds elements {256*r + 4*L + c} for r in 0..3, c in 0..3.
// t is wave-uniform -> the reg/comp selects are scalar branches, then one shfl.
__device__ __forceinline__ float extract_elem(float4 v0, float4 v1, float4 v2, float4 v3, int t) {
    int reg  = t >> 8;
    int comp = t & 3;
    float4 vr = (reg == 0) ? v0 : (reg == 1) ? v1 : (reg == 2) ? v2 : v3;
    float  x  = (comp == 0) ? vr.x : (comp == 1) ? vr.y : (comp == 2) ? vr.z : vr.w;
    return __shfl(x, (t >> 2) & 63);
}

// ---------------- Kernel 3: per-row softmax + focal loss -> per-block partials ----------------
// One 64-lane wave per row-pair; 4 waves/block; each wave owns a contiguous chunk of rows.
__global__ __launch_bounds__(256) void loss_kernel(const float* __restrict__ inp,
                                                   const int* __restrict__ tgt,
                                                   const float* __restrict__ w,
                                                   float* __restrict__ partials,
                                                   int B) {
    const int wave   = threadIdx.x >> 6;
    const int lane   = threadIdx.x & 63;
    const int gwave  = blockIdx.x * 4 + wave;
    const int nwaves = gridDim.x * 4;
    const int rpw    = (B + nwaves - 1) / nwaves;     // rows per wave (8 at B=65536)
    const int base   = gwave * rpw;
    const int lim    = (base + rpw < B) ? (base + rpw) : B;

    float acc = 0.0f;   // wave-uniform accumulator
    int r = base;
    for (; r + 1 < lim; r += 2) {
        const float4* rp0 = (const float4*)(inp + (size_t)r * NCLS);
        const float4* rp1 = (const float4*)(inp + (size_t)(r + 1) * NCLS);
        float4 a0 = rp0[lane], a1 = rp0[lane + 64], a2 = rp0[lane + 128], a3 = rp0[lane + 192];
        float4 b0 = rp1[lane], b1 = rp1[lane + 64], b2 = rp1[lane + 128], b3 = rp1[lane + 192];

        float m0 = max16(a0, a1, a2, a3);
        float m1 = max16(b0, b1, b2, b3);
        #pragma unroll
        for (int off = 32; off > 0; off >>= 1) {
            m0 = fmaxf(m0, __shfl_xor(m0, off));
            m1 = fmaxf(m1, __shfl_xor(m1, off));
        }
        float s0 = sumexp16(a0, a1, a2, a3, m0);
        float s1 = sumexp16(b0, b1, b2, b3, m1);
        #pragma unroll
        for (int off = 32; off > 0; off >>= 1) {
            s0 += __shfl_xor(s0, off);
            s1 += __shfl_xor(s1, off);
        }
        int t0 = tgt[r] & (NCLS - 1);
        int t1 = tgt[r + 1] & (NCLS - 1);
        float x0 = extract_elem(a0, a1, a2, a3, t0);
        float x1 = extract_elem(b0, b1, b2, b3, t1);
        float lp0 = x0 - (m0 + __logf(s0));
        float lp1 = x1 - (m1 + __logf(s1));
        float p0 = __expf(lp0), p1 = __expf(lp1);
        float o0 = 1.0f - p0,  o1 = 1.0f - p1;
        acc += -o0 * o0 * lp0 * w[t0] - o1 * o1 * lp1 * w[t1];
    }
    // tail (only hit when B not divisible; wave-uniform branch)
    for (; r < lim; ++r) {
        const float4* rp0 = (const float4*)(inp + (size_t)r * NCLS);
        float4 a0 = rp0[lane], a1 = rp0[lane + 64], a2 = rp0[lane + 128], a3 = rp0[lane + 192];
        float m0 = max16(a0, a1, a2, a3);
        #pragma unroll
        for (int off = 32; off > 0; off >>= 1) m0 = fmaxf(m0, __shfl_xor(m0, off));
        float s0 = sumexp16(a0, a1, a2, a3, m0);
        #pragma unroll
        for (int off = 32; off > 0; off >>= 1) s0 += __shfl_xor(s0, off);
        int t0 = tgt[r] & (NCLS - 1);
        float x0 = extract_elem(a0, a1, a2, a3, t0);
        float lp0 = x0 - (m0 + __logf(s0));
        float p0 = __expf(lp0);
        float o0 = 1.0f - p0;
        acc += -o0 * o0 * lp0 * w[t0];
    }

    __shared__ float sm[4];
    if (lane == 0) sm[wave] = acc;
    __syncthreads();
    if (threadIdx.x == 0)
        partials[blockIdx.x] = sm[0] + sm[1] + sm[2] + sm[3];
}

// ---------------- Kernel 4: reduce partials + finalize ----------------
__global__ __launch_bounds__(1024) void reduce_finalize(const float* __restrict__ partials,
                                                        float* __restrict__ out,
                                                        int n, float invB) {
    __shared__ float sm[16];
    float s = 0.0f;
    for (int i = threadIdx.x; i < n; i += 1024) s += partials[i];
    #pragma unroll
    for (int off = 32; off > 0; off >>= 1) s += __shfl_xor(s, off);
    if ((threadIdx.x & 63) == 0) sm[threadIdx.x >> 6] = s;
    __syncthreads();
    if (threadIdx.x == 0) {
        float t = 0.0f;
        #pragma unroll
        for (int i = 0; i < 16; ++i) t += sm[i];
        out[0] = t * invB;
    }
}

extern "C" void kernel_launch(void* const* d_in, const int* in_sizes, int n_in,
                              void* d_out, int out_size, void* d_ws, size_t ws_size,
                              hipStream_t stream) {
    const float* inp = (const float*)d_in[0];
    const int*   tgt = (const int*)d_in[1];
    const int B = in_sizes[1];          // 65536

    unsigned int* counts   = (unsigned int*)d_ws;
    float*        w        = (float*)((char*)d_ws + 4096);
    float*        partials = (float*)((char*)d_ws + 8192);   // LOSS_BLOCKS floats

    // zero the histogram each call (captured in the graph; replays re-zero)
    hipMemsetAsync(d_ws, 0, 4096, stream);

    hist_kernel<<<256, 256, 0, stream>>>(tgt, counts, B);
    weights_kernel<<<1, 1024, 0, stream>>>(counts, w);
    loss_kernel<<<LOSS_BLOCKS, 256, 0, stream>>>(inp, tgt, w, partials, B);
    reduce_finalize<<<1, 1024, 0, stream>>>(partials, (float*)d_out,
                                            LOSS_BLOCKS, 1.0f / (float)B);
}

// Round 3
// 53.309 us; speedup vs baseline: 4.4310x; 1.1513x over previous
//
#include <hip/hip_runtime.h>

#define NCLS 1024
#define EPS_C 1e-5f
#define LOSS_BLOCKS 2048   // 2048 blocks * 4 waves * 8 rows/wave = 65536 rows

// ---------------- Kernel 1: fused histogram + min + weights (single block) ----------------
__global__ __launch_bounds__(1024) void hist_weights_kernel(const int* __restrict__ tgt,
                                                            float* __restrict__ w,
                                                            int B) {
    __shared__ unsigned int h[NCLS];
    __shared__ float smin[16];
    const int tid = threadIdx.x;
    h[tid] = 0u;
    __syncthreads();

    const int4* t4 = (const int4*)tgt;
    const int n4 = B >> 2;
    for (int i = tid; i < n4; i += 1024) {
        int4 v = t4[i];
        atomicAdd(&h[v.x & (NCLS - 1)], 1u);
        atomicAdd(&h[v.y & (NCLS - 1)], 1u);
        atomicAdd(&h[v.z & (NCLS - 1)], 1u);
        atomicAdd(&h[v.w & (NCLS - 1)], 1u);
    }
    __syncthreads();

    float c = (float)h[tid];
    float m = c;
    #pragma unroll
    for (int off = 32; off > 0; off >>= 1) m = fminf(m, __shfl_xor(m, off));
    if ((tid & 63) == 0) smin[tid >> 6] = m;
    __syncthreads();
    if (tid == 0) {
        float mm = smin[0];
        #pragma unroll
        for (int i = 1; i < 16; ++i) mm = fminf(mm, smin[i]);
        smin[0] = mm;
    }
    __syncthreads();
    w[tid] = smin[0] / c + EPS_C;
}

// ---------------- helpers ----------------
__device__ __forceinline__ float sumexp16(float4 a, float4 b, float4 c, float4 d) {
    return __expf(a.x) + __expf(a.y) + __expf(a.z) + __expf(a.w)
         + __expf(b.x) + __expf(b.y) + __expf(b.z) + __expf(b.w)
         + __expf(c.x) + __expf(c.y) + __expf(c.z) + __expf(c.w)
         + __expf(d.x) + __expf(d.y) + __expf(d.z) + __expf(d.w);
}

// ---------------- Kernel 2: per-row sum-exp + focal loss -> per-block partials ----------------
// 8 rows per wave: zero cross-lane work in the streaming loop, one ILP-8 butterfly after.
__global__ __launch_bounds__(256) void loss_kernel(const float* __restrict__ inp,
                                                   const int* __restrict__ tgt,
                                                   const float* __restrict__ w,
                                                   float* __restrict__ partials,
                                                   int B) {
    const int wave  = threadIdx.x >> 6;
    const int lane  = threadIdx.x & 63;
    const int gwave = blockIdx.x * 4 + wave;
    const int base  = gwave * 8;

    float acc = 0.0f;

    if (base + 8 <= B) {
        float s[8];
        const float4* rp = (const float4*)(inp + (size_t)base * NCLS);
        #pragma unroll
        for (int rr = 0; rr < 8; ++rr) {
            float4 a0 = rp[lane];
            float4 a1 = rp[lane + 64];
            float4 a2 = rp[lane + 128];
            float4 a3 = rp[lane + 192];
            s[rr] = sumexp16(a0, a1, a2, a3);
            rp += NCLS / 4;     // next row
        }
        // one butterfly, 8 independent chains
        #pragma unroll
        for (int off = 32; off > 0; off >>= 1) {
            #pragma unroll
            for (int rr = 0; rr < 8; ++rr) s[rr] += __shfl_xor(s[rr], off);
        }
        // lane r (r<8) takes row base+r (compile-time-indexed select, no scratch)
        float myS = s[0];
        #pragma unroll
        for (int rr = 1; rr < 8; ++rr) myS = (lane == rr) ? s[rr] : myS;

        float l = 0.0f;
        if (lane < 8) {
            const int row = base + lane;
            const int t = tgt[row] & (NCLS - 1);
            const float xt = inp[(size_t)row * NCLS + t];   // L2-hot gather
            const float lp = xt - __logf(myS);
            const float p  = __expf(lp);
            const float o  = 1.0f - p;
            l = -o * o * lp * w[t];
        }
        l += __shfl_xor(l, 1);
        l += __shfl_xor(l, 2);
        l += __shfl_xor(l, 4);
        acc = l;        // lanes 0..7 all hold the 8-row total
    } else {
        // generic tail (dead at B=65536)
        for (int r = base; r < B && r < base + 8; ++r) {
            const float4* rp = (const float4*)(inp + (size_t)r * NCLS);
            float4 a0 = rp[lane], a1 = rp[lane + 64], a2 = rp[lane + 128], a3 = rp[lane + 192];
            float s0 = sumexp16(a0, a1, a2, a3);
            #pragma unroll
            for (int off = 32; off > 0; off >>= 1) s0 += __shfl_xor(s0, off);
            const int t = tgt[r] & (NCLS - 1);
            const float xt = inp[(size_t)r * NCLS + t];
            const float lp = xt - __logf(s0);
            const float p  = __expf(lp);
            const float o  = 1.0f - p;
            acc += -o * o * lp * w[t];
        }
    }

    __shared__ float sm[4];
    if (lane == 0) sm[wave] = acc;
    __syncthreads();
    if (threadIdx.x == 0)
        partials[blockIdx.x] = sm[0] + sm[1] + sm[2] + sm[3];
}

// ---------------- Kernel 3: reduce partials + finalize ----------------
__global__ __launch_bounds__(1024) void reduce_finalize(const float* __restrict__ partials,
                                                        float* __restrict__ out,
                                                        int n, float invB) {
    __shared__ float sm[16];
    float s = 0.0f;
    for (int i = threadIdx.x; i < n; i += 1024) s += partials[i];
    #pragma unroll
    for (int off = 32; off > 0; off >>= 1) s += __shfl_xor(s, off);
    if ((threadIdx.x & 63) == 0) sm[threadIdx.x >> 6] = s;
    __syncthreads();
    if (threadIdx.x == 0) {
        float t = 0.0f;
        #pragma unroll
        for (int i = 0; i < 16; ++i) t += sm[i];
        out[0] = t * invB;
    }
}

extern "C" void kernel_launch(void* const* d_in, const int* in_sizes, int n_in,
                              void* d_out, int out_size, void* d_ws, size_t ws_size,
                              hipStream_t stream) {
    const float* inp = (const float*)d_in[0];
    const int*   tgt = (const int*)d_in[1];
    const int B = in_sizes[1];          // 65536

    float* w        = (float*)d_ws;                       // 1024 floats
    float* partials = (float*)((char*)d_ws + 4096);       // LOSS_BLOCKS floats

    hist_weights_kernel<<<1, 1024, 0, stream>>>(tgt, w, B);
    loss_kernel<<<LOSS_BLOCKS, 256, 0, stream>>>(inp, tgt, w, partials, B);
    reduce_finalize<<<1, 1024, 0, stream>>>(partials, (float*)d_out,
                                            LOSS_BLOCKS, 1.0f / (float)B);
}